// Round 1
// baseline (375.399 us; speedup 1.0000x reference)
//
#include <hip/hip_runtime.h>
#include <hip/hip_bf16.h>
#include <stdint.h>

#define B_DIM 128
#define N_DIM 16384
#define E_DIM 1048576
#define H_DIM 512
#define C_DIM 10
#define SPLITK 64
#define KC (N_DIM / SPLITK)   // 256
#define BM 64
#define KB 16

// ---------- transpose x (B,N) -> xT (N,B) ----------
__global__ void k_transpose(const float* __restrict__ x, float* __restrict__ xT) {
    __shared__ float tile[32][33];
    int bx = blockIdx.x, by = blockIdx.y;
    int tx = threadIdx.x, ty = threadIdx.y;
    int n = bx * 32 + tx, b = by * 32 + ty;
    tile[ty][tx] = x[b * N_DIM + n];
    __syncthreads();
    int n2 = bx * 32 + ty, b2 = by * 32 + tx;
    xT[n2 * B_DIM + b2] = tile[tx][ty];
}

// ---------- histogram of dst + weighted in-degree ----------
__global__ void k_hist(const int* __restrict__ dst, const float* __restrict__ ew,
                       int* __restrict__ hist, float* __restrict__ degw) {
    int e = blockIdx.x * blockDim.x + threadIdx.x;
    if (e < E_DIM) {
        int d = dst[e];
        atomicAdd(&hist[d], 1);
        atomicAdd(&degw[d], ew[e]);
    }
}

// ---------- exclusive scan of hist + dinv ----------
__global__ void __launch_bounds__(1024) k_scan(const int* __restrict__ hist,
                                               const float* __restrict__ degw,
                                               int* __restrict__ offs, int* __restrict__ cursor,
                                               float* __restrict__ dinv) {
    __shared__ int part[1024];
    int t = threadIdx.x;
    int base = t * 16;
    int loc[16];
    int s = 0;
#pragma unroll
    for (int i = 0; i < 16; i++) { loc[i] = s; s += hist[base + i]; }
    part[t] = s;
    __syncthreads();
    for (int off = 1; off < 1024; off <<= 1) {
        int v = (t >= off) ? part[t - off] : 0;
        __syncthreads();
        part[t] += v;
        __syncthreads();
    }
    int ex = (t == 0) ? 0 : part[t - 1];
#pragma unroll
    for (int i = 0; i < 16; i++) {
        int o = ex + loc[i];
        offs[base + i] = o;
        cursor[base + i] = o;
    }
    if (t == 1023) offs[N_DIM] = part[1023];
#pragma unroll
    for (int i = 0; i < 16; i++) {
        // deg includes self-loop weight 1; always > 0
        dinv[base + i] = 1.0f / sqrtf(degw[base + i] + 1.0f);
    }
}

// ---------- place edges into dst-sorted CSR, norm precomputed ----------
__global__ void k_place(const int* __restrict__ src, const int* __restrict__ dst,
                        const float* __restrict__ ew, const float* __restrict__ dinv,
                        int* __restrict__ cursor, int2* __restrict__ packed) {
    int e = blockIdx.x * blockDim.x + threadIdx.x;
    if (e < E_DIM) {
        int s = src[e], d = dst[e];
        float nrm = dinv[s] * ew[e] * dinv[d];
        int pos = atomicAdd(&cursor[d], 1);
        packed[pos] = make_int2(s, __float_as_int(nrm));
    }
}

// ---------- heavy diffusion: one wave per destination node ----------
__global__ void __launch_bounds__(64) k_diffuse(const float* __restrict__ xT,
                                                const int* __restrict__ offs,
                                                const int2* __restrict__ packed,
                                                const float* __restrict__ dinv,
                                                float* __restrict__ hT) {
    int d = blockIdx.x;
    int lane = threadIdx.x;
    __shared__ int2 buf[64];
    const float2* x2 = (const float2*)xT;
    float dv = dinv[d];
    float selfw = dv * dv;          // self-loop: dinv[d]*1*dinv[d]
    float2 xv = x2[d * 64 + lane];
    float2 acc = make_float2(xv.x * selfw, xv.y * selfw);
    int e0 = offs[d], e1 = offs[d + 1];
    for (int base = e0; base < e1; base += 64) {
        int cnt = e1 - base;
        if (cnt > 64) cnt = 64;
        if (lane < cnt) buf[lane] = packed[base + lane];
        __syncthreads();
        for (int i = 0; i < cnt; i++) {
            int2 p = buf[i];
            float nrm = __int_as_float(p.y);
            float2 xs = x2[p.x * 64 + lane];
            acc.x = fmaf(nrm, xs.x, acc.x);
            acc.y = fmaf(nrm, xs.y, acc.y);
        }
        __syncthreads();
    }
    ((float2*)hT)[d * 64 + lane] = acc;
}

// ---------- GEMM1: W1(512,16384) x hT(16384,128) split-K partials ----------
__global__ void __launch_bounds__(256) k_gemm1(const float* __restrict__ W1,
                                               const float* __restrict__ hT,
                                               float* __restrict__ part) {
    int mt = blockIdx.x;   // 0..7
    int kc = blockIdx.y;   // 0..SPLITK-1
    int t = threadIdx.x;
    __shared__ float Ws[KB][BM];     // 16 x 64
    __shared__ float Hs[KB][B_DIM];  // 16 x 128
    int tn = t & 31;   // col group (*4)
    int tm = t >> 5;   // row group (*8)
    float acc[8][4];
#pragma unroll
    for (int i = 0; i < 8; i++)
#pragma unroll
        for (int j = 0; j < 4; j++) acc[i][j] = 0.f;
    int m0 = mt * BM;
    int k0 = kc * KC;
    int wr = t >> 2;         // 0..63 W row
    int wq = (t & 3) * 4;    // k quad
    int hr = t >> 4;         // 0..15 k row
    int hc = (t & 15) * 8;   // col (*8)
    for (int ks = 0; ks < KC; ks += KB) {
        float4 wv = *(const float4*)&W1[(size_t)(m0 + wr) * N_DIM + k0 + ks + wq];
        float4 h0 = *(const float4*)&hT[(k0 + ks + hr) * B_DIM + hc];
        float4 h1 = *(const float4*)&hT[(k0 + ks + hr) * B_DIM + hc + 4];
        __syncthreads();
        Ws[wq + 0][wr] = wv.x;
        Ws[wq + 1][wr] = wv.y;
        Ws[wq + 2][wr] = wv.z;
        Ws[wq + 3][wr] = wv.w;
        *(float4*)&Hs[hr][hc] = h0;
        *(float4*)&Hs[hr][hc + 4] = h1;
        __syncthreads();
#pragma unroll
        for (int kk = 0; kk < KB; kk++) {
            float a[8], b[4];
            *(float4*)&a[0] = *(const float4*)&Ws[kk][tm * 8];
            *(float4*)&a[4] = *(const float4*)&Ws[kk][tm * 8 + 4];
            *(float4*)&b[0] = *(const float4*)&Hs[kk][tn * 4];
#pragma unroll
            for (int i = 0; i < 8; i++)
#pragma unroll
                for (int j = 0; j < 4; j++)
                    acc[i][j] = fmaf(a[i], b[j], acc[i][j]);
        }
    }
    float* pbase = part + (size_t)kc * (H_DIM * B_DIM);
#pragma unroll
    for (int i = 0; i < 8; i++)
        *(float4*)&pbase[(m0 + tm * 8 + i) * B_DIM + tn * 4] = *(float4*)&acc[i][0];
}

// ---------- reduce split-K partials + bias + relu ----------
__global__ void k_reduce1(const float* __restrict__ part, const float* __restrict__ b1,
                          float* __restrict__ h1T) {
    int idx = blockIdx.x * 256 + threadIdx.x;  // 0..65535
    int j = idx >> 7;
    float s = b1[j];
#pragma unroll
    for (int c = 0; c < SPLITK; c++) s += part[c * (H_DIM * B_DIM) + idx];
    h1T[idx] = fmaxf(s, 0.f);
}

// ---------- GEMM2: W2(512,512) x h1T(512,128) + relu ----------
__global__ void __launch_bounds__(256) k_gemm2(const float* __restrict__ W2,
                                               const float* __restrict__ b2,
                                               const float* __restrict__ h1T,
                                               float* __restrict__ h2T) {
    int t = threadIdx.x;
    int b = t & 127;
    int j = blockIdx.x * 2 + (t >> 7);
    const float* wrow = W2 + j * H_DIM;
    float s = b2[j];
#pragma unroll 4
    for (int i = 0; i < H_DIM; i++)
        s = fmaf(wrow[i], h1T[i * B_DIM + b], s);
    h2T[j * B_DIM + b] = fmaxf(s, 0.f);
}

// ---------- GEMM3: Wfc(10,512) x h2T(512,128) -> out (128,10) ----------
__global__ void __launch_bounds__(128) k_gemm3(const float* __restrict__ Wfc,
                                               const float* __restrict__ bfc,
                                               const float* __restrict__ h2T,
                                               float* __restrict__ out) {
    int c = blockIdx.x;
    int b = threadIdx.x;
    const float* wrow = Wfc + c * H_DIM;
    float s = bfc[c];
#pragma unroll 4
    for (int i = 0; i < H_DIM; i++)
        s = fmaf(wrow[i], h2T[i * B_DIM + b], s);
    out[b * C_DIM + c] = s;
}

extern "C" void kernel_launch(void* const* d_in, const int* in_sizes, int n_in,
                              void* d_out, int out_size, void* d_ws, size_t ws_size,
                              hipStream_t stream) {
    const float* x   = (const float*)d_in[0];
    const int*   ei  = (const int*)d_in[1];
    const float* ew  = (const float*)d_in[2];
    const float* W1  = (const float*)d_in[3];
    const float* b1  = (const float*)d_in[4];
    const float* W2  = (const float*)d_in[5];
    const float* b2  = (const float*)d_in[6];
    const float* Wfc = (const float*)d_in[7];
    const float* bfc = (const float*)d_in[8];
    float* out = (float*)d_out;

    const int* src = ei;
    const int* dst = ei + E_DIM;

    char* ws = (char*)d_ws;
    size_t off = 0;
    auto alloc = [&](size_t bytes) -> void* {
        void* p = ws + off;
        off = (off + bytes + 255) & ~(size_t)255;
        return p;
    };
    float* xT     = (float*)alloc((size_t)N_DIM * B_DIM * 4);   // 8 MB
    float* hT     = (float*)alloc((size_t)N_DIM * B_DIM * 4);   // 8 MB
    int2*  packed = (int2*) alloc((size_t)E_DIM * 8);           // 8 MB
    float* part   = (float*)alloc((size_t)SPLITK * H_DIM * B_DIM * 4); // 16 MB
    float* h1T    = (float*)alloc((size_t)H_DIM * B_DIM * 4);
    float* h2T    = (float*)alloc((size_t)H_DIM * B_DIM * 4);
    int*   hist   = (int*)  alloc((size_t)(N_DIM + 1) * 4);
    int*   offs   = (int*)  alloc((size_t)(N_DIM + 1) * 4);
    int*   cursor = (int*)  alloc((size_t)N_DIM * 4);
    float* degw   = (float*)alloc((size_t)N_DIM * 4);
    float* dinv   = (float*)alloc((size_t)N_DIM * 4);
    if (off > ws_size) return;  // workspace too small; fail loudly via validation

    hipMemsetAsync(hist, 0, (size_t)(N_DIM + 1) * 4, stream);
    hipMemsetAsync(degw, 0, (size_t)N_DIM * 4, stream);

    k_transpose<<<dim3(N_DIM / 32, B_DIM / 32), dim3(32, 32), 0, stream>>>(x, xT);
    k_hist<<<E_DIM / 256, 256, 0, stream>>>(dst, ew, hist, degw);
    k_scan<<<1, 1024, 0, stream>>>(hist, degw, offs, cursor, dinv);
    k_place<<<E_DIM / 256, 256, 0, stream>>>(src, dst, ew, dinv, cursor, packed);
    k_diffuse<<<N_DIM, 64, 0, stream>>>(xT, offs, packed, dinv, hT);
    k_gemm1<<<dim3(H_DIM / BM, SPLITK), 256, 0, stream>>>(W1, hT, part);
    k_reduce1<<<(H_DIM * B_DIM) / 256, 256, 0, stream>>>(part, b1, h1T);
    k_gemm2<<<H_DIM / 2, 256, 0, stream>>>(W2, b2, h1T, h2T);
    k_gemm3<<<C_DIM, 128, 0, stream>>>(Wfc, bfc, h2T, out);
}

// Round 2
// 233.521 us; speedup vs baseline: 1.6076x; 1.6076x over previous
//
#include <hip/hip_runtime.h>
#include <hip/hip_bf16.h>
#include <stdint.h>

#define B_DIM 128
#define N_DIM 16384
#define E_DIM 1048576
#define H_DIM 512
#define C_DIM 10
#define NWG 256               // wgs for hist/place
#define CHUNK (E_DIM / NWG)   // 4096 edges per wg
#define NWORD (N_DIM / 2)     // 8192 packed uint words (2 bins each)
#define SPLITK 64
#define KC (N_DIM / SPLITK)   // 256
#define BM 64
#define KB 16

// ---------- transpose x (B,N) -> xT (N,B) ----------
__global__ void k_transpose(const float* __restrict__ x, float* __restrict__ xT) {
    __shared__ float tile[32][33];
    int bx = blockIdx.x, by = blockIdx.y;
    int tx = threadIdx.x, ty = threadIdx.y;
    int n = bx * 32 + tx, b = by * 32 + ty;
    tile[ty][tx] = x[b * N_DIM + n];
    __syncthreads();
    int n2 = bx * 32 + ty, b2 = by * 32 + tx;
    xT[n2 * B_DIM + b2] = tile[tx][ty];
}

// ---------- per-wg LDS histogram of dst (2x16-bit packed), flush to slab ----------
__global__ void __launch_bounds__(256) k_hist1(const int* __restrict__ dst,
                                               uint32_t* __restrict__ slab) {
    __shared__ uint32_t lh[NWORD];   // 32 KB
    int w = blockIdx.x, t = threadIdx.x;
#pragma unroll
    for (int i = 0; i < NWORD / 256; i++) lh[i * 256 + t] = 0;
    __syncthreads();
#pragma unroll
    for (int i = 0; i < CHUNK / 256; i++) {
        int d = dst[w * CHUNK + i * 256 + t];
        atomicAdd(&lh[d >> 1], 1u << ((d & 1) << 4));
    }
    __syncthreads();
#pragma unroll
    for (int i = 0; i < NWORD / 256; i++)
        slab[(size_t)w * NWORD + i * 256 + t] = lh[i * 256 + t];
}

// ---------- slab -> in-place within-bin per-wg exclusive prefix; bin totals ----------
__global__ void __launch_bounds__(256) k_scan2a(uint32_t* __restrict__ slab,
                                                uint32_t* __restrict__ binTot) {
    int j = blockIdx.x * 256 + threadIdx.x;   // word 0..8191
    uint32_t lo = 0, hi = 0;
    for (int w = 0; w < NWG; w++) {
        uint32_t c = slab[(size_t)w * NWORD + j];
        slab[(size_t)w * NWORD + j] = lo | (hi << 16);
        lo += c & 0xffffu;
        hi += c >> 16;
    }
    binTot[j] = lo | (hi << 16);   // per-bin totals (max ~150 each, fits 16b)
}

// ---------- single-wg exclusive scan of bin totals -> CSR offs ----------
__global__ void __launch_bounds__(1024) k_scan2b(const uint32_t* __restrict__ binTot,
                                                 int* __restrict__ offs) {
    __shared__ uint32_t part[1024];
    int t = threadIdx.x;
    uint32_t loc[16];
    uint32_t s = 0;
    int wbase = t * 8;
#pragma unroll
    for (int i = 0; i < 8; i++) {
        uint32_t wv = binTot[wbase + i];
        loc[2 * i] = s;     s += (wv & 0xffffu);
        loc[2 * i + 1] = s; s += (wv >> 16);
    }
    part[t] = s;
    __syncthreads();
    for (int off = 1; off < 1024; off <<= 1) {
        uint32_t v = (t >= off) ? part[t - off] : 0;
        __syncthreads();
        part[t] += v;
        __syncthreads();
    }
    uint32_t ex = (t == 0) ? 0 : part[t - 1];
#pragma unroll
    for (int i = 0; i < 16; i++) offs[t * 16 + i] = (int)(ex + loc[i]);
    if (t == 1023) offs[N_DIM] = (int)part[1023];
}

// ---------- atomic-free (global) placement: LDS cursor per wg ----------
__global__ void __launch_bounds__(256) k_place2(const int* __restrict__ src,
                                                const int* __restrict__ dst,
                                                const float* __restrict__ ew,
                                                const uint32_t* __restrict__ slab,
                                                const int* __restrict__ offs,
                                                int2* __restrict__ packed) {
    __shared__ uint32_t cur[N_DIM];   // 64 KB
    int w = blockIdx.x, t = threadIdx.x;
#pragma unroll
    for (int i = 0; i < NWORD / 256; i++) {
        int j = i * 256 + t;
        uint32_t pv = slab[(size_t)w * NWORD + j];
        int2 o = *(const int2*)&offs[2 * j];
        cur[2 * j]     = (uint32_t)o.x + (pv & 0xffffu);
        cur[2 * j + 1] = (uint32_t)o.y + (pv >> 16);
    }
    __syncthreads();
#pragma unroll
    for (int i = 0; i < CHUNK / 256; i++) {
        int e = w * CHUNK + i * 256 + t;
        int s = src[e], d = dst[e];
        uint32_t pos = atomicAdd(&cur[d], 1u);   // LDS atomic
        packed[pos] = make_int2(s, __float_as_int(ew[e]));
    }
}

// ---------- per-node weighted in-degree from sorted segments -> dinv ----------
__global__ void __launch_bounds__(64) k_deg(const int* __restrict__ offs,
                                            const int2* __restrict__ packed,
                                            float* __restrict__ dinv) {
    int d = blockIdx.x, lane = threadIdx.x;
    int e0 = offs[d], e1 = offs[d + 1];
    float s = 0.f;
    for (int e = e0 + lane; e < e1; e += 64)
        s += __int_as_float(packed[e].y);
#pragma unroll
    for (int off = 32; off > 0; off >>= 1) s += __shfl_down(s, off);
    if (lane == 0) dinv[d] = rsqrtf(s + 1.0f);   // + self-loop weight 1; always > 0
}

// ---------- fold dinv[src]*w into packed (dinv[d] factors out of the sum) ----------
__global__ void k_norm(const float* __restrict__ dinv, int2* __restrict__ packed) {
    int e = blockIdx.x * 256 + threadIdx.x;
    int2 p = packed[e];
    float w = __int_as_float(p.y);
    packed[e].y = __float_as_int(dinv[p.x] * w);
}

// ---------- heavy diffusion: one wave per destination node ----------
__global__ void __launch_bounds__(64) k_diffuse(const float* __restrict__ xT,
                                                const int* __restrict__ offs,
                                                const int2* __restrict__ packed,
                                                const float* __restrict__ dinv,
                                                float* __restrict__ hT) {
    int d = blockIdx.x;
    int lane = threadIdx.x;
    __shared__ int2 buf[64];
    const float2* x2 = (const float2*)xT;
    float dv = dinv[d];
    float2 xv = x2[d * 64 + lane];
    float2 acc = make_float2(xv.x * dv, xv.y * dv);   // self-loop: dv^2*x after final *dv
    int e0 = offs[d], e1 = offs[d + 1];
    for (int base = e0; base < e1; base += 64) {
        int cnt = e1 - base;
        if (cnt > 64) cnt = 64;
        if (lane < cnt) buf[lane] = packed[base + lane];
        __syncthreads();
        for (int i = 0; i < cnt; i++) {
            int2 p = buf[i];
            float nrm = __int_as_float(p.y);   // dinv[s]*w
            float2 xs = x2[p.x * 64 + lane];
            acc.x = fmaf(nrm, xs.x, acc.x);
            acc.y = fmaf(nrm, xs.y, acc.y);
        }
        __syncthreads();
    }
    acc.x *= dv; acc.y *= dv;
    ((float2*)hT)[d * 64 + lane] = acc;
}

// ---------- GEMM1: W1(512,16384) x hT(16384,128) split-K partials ----------
__global__ void __launch_bounds__(256) k_gemm1(const float* __restrict__ W1,
                                               const float* __restrict__ hT,
                                               float* __restrict__ part) {
    int mt = blockIdx.x;   // 0..7
    int kc = blockIdx.y;   // 0..SPLITK-1
    int t = threadIdx.x;
    __shared__ float Ws[KB][BM];     // 16 x 64
    __shared__ float Hs[KB][B_DIM];  // 16 x 128
    int tn = t & 31;   // col group (*4)
    int tm = t >> 5;   // row group (*8)
    float acc[8][4];
#pragma unroll
    for (int i = 0; i < 8; i++)
#pragma unroll
        for (int j = 0; j < 4; j++) acc[i][j] = 0.f;
    int m0 = mt * BM;
    int k0 = kc * KC;
    int wr = t >> 2;         // 0..63 W row
    int wq = (t & 3) * 4;    // k quad
    int hr = t >> 4;         // 0..15 k row
    int hc = (t & 15) * 8;   // col (*8)
    for (int ks = 0; ks < KC; ks += KB) {
        float4 wv = *(const float4*)&W1[(size_t)(m0 + wr) * N_DIM + k0 + ks + wq];
        float4 h0 = *(const float4*)&hT[(k0 + ks + hr) * B_DIM + hc];
        float4 h1 = *(const float4*)&hT[(k0 + ks + hr) * B_DIM + hc + 4];
        __syncthreads();
        Ws[wq + 0][wr] = wv.x;
        Ws[wq + 1][wr] = wv.y;
        Ws[wq + 2][wr] = wv.z;
        Ws[wq + 3][wr] = wv.w;
        *(float4*)&Hs[hr][hc] = h0;
        *(float4*)&Hs[hr][hc + 4] = h1;
        __syncthreads();
#pragma unroll
        for (int kk = 0; kk < KB; kk++) {
            float a[8], b[4];
            *(float4*)&a[0] = *(const float4*)&Ws[kk][tm * 8];
            *(float4*)&a[4] = *(const float4*)&Ws[kk][tm * 8 + 4];
            *(float4*)&b[0] = *(const float4*)&Hs[kk][tn * 4];
#pragma unroll
            for (int i = 0; i < 8; i++)
#pragma unroll
                for (int j = 0; j < 4; j++)
                    acc[i][j] = fmaf(a[i], b[j], acc[i][j]);
        }
    }
    float* pbase = part + (size_t)kc * (H_DIM * B_DIM);
#pragma unroll
    for (int i = 0; i < 8; i++)
        *(float4*)&pbase[(m0 + tm * 8 + i) * B_DIM + tn * 4] = *(float4*)&acc[i][0];
}

// ---------- reduce split-K partials + bias + relu ----------
__global__ void k_reduce1(const float* __restrict__ part, const float* __restrict__ b1,
                          float* __restrict__ h1T) {
    int idx = blockIdx.x * 256 + threadIdx.x;  // 0..65535
    int j = idx >> 7;
    float s = b1[j];
#pragma unroll
    for (int c = 0; c < SPLITK; c++) s += part[c * (H_DIM * B_DIM) + idx];
    h1T[idx] = fmaxf(s, 0.f);
}

// ---------- GEMM2: W2(512,512) x h1T(512,128) + relu ----------
__global__ void __launch_bounds__(256) k_gemm2(const float* __restrict__ W2,
                                               const float* __restrict__ b2,
                                               const float* __restrict__ h1T,
                                               float* __restrict__ h2T) {
    int t = threadIdx.x;
    int b = t & 127;
    int j = blockIdx.x * 2 + (t >> 7);
    const float* wrow = W2 + j * H_DIM;
    float s = b2[j];
#pragma unroll 4
    for (int i = 0; i < H_DIM; i++)
        s = fmaf(wrow[i], h1T[i * B_DIM + b], s);
    h2T[j * B_DIM + b] = fmaxf(s, 0.f);
}

// ---------- GEMM3: Wfc(10,512) x h2T(512,128) -> out (128,10) ----------
__global__ void __launch_bounds__(128) k_gemm3(const float* __restrict__ Wfc,
                                               const float* __restrict__ bfc,
                                               const float* __restrict__ h2T,
                                               float* __restrict__ out) {
    int c = blockIdx.x;
    int b = threadIdx.x;
    const float* wrow = Wfc + c * H_DIM;
    float s = bfc[c];
#pragma unroll 4
    for (int i = 0; i < H_DIM; i++)
        s = fmaf(wrow[i], h2T[i * B_DIM + b], s);
    out[b * C_DIM + c] = s;
}

extern "C" void kernel_launch(void* const* d_in, const int* in_sizes, int n_in,
                              void* d_out, int out_size, void* d_ws, size_t ws_size,
                              hipStream_t stream) {
    const float* x   = (const float*)d_in[0];
    const int*   ei  = (const int*)d_in[1];
    const float* ew  = (const float*)d_in[2];
    const float* W1  = (const float*)d_in[3];
    const float* b1  = (const float*)d_in[4];
    const float* W2  = (const float*)d_in[5];
    const float* b2  = (const float*)d_in[6];
    const float* Wfc = (const float*)d_in[7];
    const float* bfc = (const float*)d_in[8];
    float* out = (float*)d_out;

    const int* src = ei;
    const int* dst = ei + E_DIM;

    char* ws = (char*)d_ws;
    size_t off = 0;
    auto alloc = [&](size_t bytes) -> void* {
        void* p = ws + off;
        off = (off + bytes + 255) & ~(size_t)255;
        return p;
    };
    float* xT     = (float*)alloc((size_t)N_DIM * B_DIM * 4);          // 8 MB
    float* hT     = (float*)alloc((size_t)N_DIM * B_DIM * 4);          // 8 MB
    int2*  packed = (int2*) alloc((size_t)E_DIM * 8);                  // 8 MB
    float* part   = (float*)alloc((size_t)SPLITK * H_DIM * B_DIM * 4); // 16 MB
    float* h1T    = (float*)alloc((size_t)H_DIM * B_DIM * 4);
    float* h2T    = (float*)alloc((size_t)H_DIM * B_DIM * 4);
    int*   offs   = (int*)  alloc((size_t)(N_DIM + 1) * 4);
    float* dinv   = (float*)alloc((size_t)N_DIM * 4);
    // slab (8 MB) + binTot (32 KB) alias the 'part' region: their lifetime
    // (hist1..place2) is disjoint from part's (gemm1..reduce1).
    uint32_t* slab   = (uint32_t*)part;
    uint32_t* binTot = (uint32_t*)((char*)part + (size_t)NWG * NWORD * 4);
    if (off > ws_size) return;

    k_transpose<<<dim3(N_DIM / 32, B_DIM / 32), dim3(32, 32), 0, stream>>>(x, xT);
    k_hist1<<<NWG, 256, 0, stream>>>(dst, slab);
    k_scan2a<<<NWORD / 256, 256, 0, stream>>>(slab, binTot);
    k_scan2b<<<1, 1024, 0, stream>>>(binTot, offs);
    k_place2<<<NWG, 256, 0, stream>>>(src, dst, ew, slab, offs, packed);
    k_deg<<<N_DIM, 64, 0, stream>>>(offs, packed, dinv);
    k_norm<<<E_DIM / 256, 256, 0, stream>>>(dinv, packed);
    k_diffuse<<<N_DIM, 64, 0, stream>>>(xT, offs, packed, dinv, hT);
    k_gemm1<<<dim3(H_DIM / BM, SPLITK), 256, 0, stream>>>(W1, hT, part);
    k_reduce1<<<(H_DIM * B_DIM) / 256, 256, 0, stream>>>(part, b1, h1T);
    k_gemm2<<<H_DIM / 2, 256, 0, stream>>>(W2, b2, h1T, h2T);
    k_gemm3<<<C_DIM, 128, 0, stream>>>(Wfc, bfc, h2T, out);
}